// Round 3
// baseline (2328.602 us; speedup 1.0000x reference)
//
#include <hip/hip_runtime.h>

// WindowAttention fused kernel for MI355X (gfx950) — R2.
// One workgroup (256 thr = 4 waves) per window block b (grid=2048), 2 wg/CU.
// R2 changes vs R1 (which was latency-bound: 1 wg/CU, 12% occupancy):
//  - LDS 163KB -> 58.4KB via phase overlays => 2 workgroups/CU.
//  - RPE terms scattered DIRECTLY into score-shaped swizzled buffers
//    (SQR[i][(jp&7)*8+(jp>>3)], SVK[ip][(j&15)*8+(j>>4)]) in the U/V MFMA
//    epilogue via inverse relidx; gathers become ld16 x8 (was 128 scalar/lane).
//  - mask pre-converted to f16 with the same swizzle => ld16 gather.
//  - x A-fragments cached in 32 VGPRs (xs LDS freed after prologue).
//  - proj accumulated incrementally per head (po regs) via tiny asb staging.

#define SCALE 0.17677669529663687f   // 32^-0.5

typedef __attribute__((ext_vector_type(8))) __bf16 bf16x8;
typedef __attribute__((ext_vector_type(8))) _Float16 f16x8;
typedef __attribute__((ext_vector_type(8))) short s16x8;
typedef __attribute__((ext_vector_type(4))) float  f32x4;

__device__ __forceinline__ float bf2f(ushort u){
  union { unsigned int i; float f; } v; v.i = ((unsigned int)u) << 16; return v.f;
}
__device__ __forceinline__ ushort f2bf(float f){
  union { float f; unsigned int i; } v; v.f = f;
  unsigned int r = v.i + 0x7FFFu + ((v.i >> 16) & 1u);   // RNE
  return (ushort)(r >> 16);
}
__device__ __forceinline__ bf16x8 ld16(const ushort* p){          // 16B-aligned
  int4 v = *(const int4*)p;
  return __builtin_bit_cast(bf16x8, v);
}
__device__ __forceinline__ f16x8 ldh16(const ushort* p){          // 16B-aligned
  int4 v = *(const int4*)p;
  return __builtin_bit_cast(f16x8, v);
}
__device__ __forceinline__ bf16x8 ld8(const ushort* p){           // 8B-aligned
  int2 lo = *(const int2*)p;
  int2 hi = *(const int2*)(p + 4);
  int4 v = make_int4(lo.x, lo.y, hi.x, hi.y);
  return __builtin_bit_cast(bf16x8, v);
}
__device__ __forceinline__ f32x4 mfma16(bf16x8 a, bf16x8 b, f32x4 c){
  return __builtin_amdgcn_mfma_f32_16x16x32_bf16(a, b, c, 0, 0, 0);
}

// ---------------- prologue kernels: bf16/f16 conversions into workspace ----
// ws layout (ushorts): wb[49152] | pwb[16384] | rpeb[240*384] | tvt[4*32*240]
//                      | mskT[128*128*128 f16]
__global__ void wa_prep(const float* __restrict__ qkv_w,
                        const float* __restrict__ rpe,
                        const float* __restrict__ proj_w,
                        ushort* __restrict__ wb, ushort* __restrict__ pwb,
                        ushort* __restrict__ rpeb, ushort* __restrict__ tvt){
  int t = blockIdx.x * 256 + threadIdx.x;
  if (t < 49152) wb[t] = f2bf(qkv_w[t]);
  if (t < 16384) pwb[t] = f2bf(proj_w[t]);
  if (t < 92160){                 // rpeb [240][384] in [3,H,32] packing;
    int r = t / 384, c = t % 384; // source table is [H][3][32] packing
    int part = c >> 7, rem = c & 127, h = rem >> 5, cc = rem & 31;
    int srcc = h * 96 + part * 32 + cc;
    float v = (r < 225) ? rpe[r * 384 + srcc] * ((part == 0) ? SCALE : 1.0f) : 0.f;
    rpeb[t] = f2bf(v);
  }
  if (t < 30720){                 // tvt [h][c 32][r 240]  (v_rpe^T)
    int r = t % 240, hc = t / 240;
    int h = hc >> 5, c = hc & 31;
    float v = (r < 225) ? rpe[r * 384 + h * 96 + 64 + c] : 0.f;
    tvt[t] = f2bf(v);
  }
}

// mskT[wi][i][c] = f16(mask[wi][i][(c&7)*16 + (c>>3)])  (swizzle for ld16 gather)
__global__ void wa_prep_mask(const float* __restrict__ mask,
                             ushort* __restrict__ mskT){
  int t = blockIdx.x * 256 + threadIdx.x;            // 2,097,152 total
  int wi = t >> 14, rem = t & 16383, i = rem >> 7, c = rem & 127;
  int j = (c & 7) * 16 + (c >> 3);
  _Float16 hv = (_Float16)mask[(wi << 14) + (i << 7) + j];
  mskT[t] = __builtin_bit_cast(ushort, hv);
}

// ---------------- main fused kernel ----------------
// LDS regions (ushort offsets into sm[29184] = 58368 B):
//  SQR  @0      [128][72]  score-shaped q.k_rpe (per-wave slabs; qsl nested)
//  SVK  @9216   [64][136]  score-shaped k.q_rpe (ksl slabs nested)
//  ps   @0      [128][136] softmax p (overlays SQR+SVK)       end 17408
//  vts  @17920  [32][136]  v transposed
//  W    @0      [128][228] p2 scatter for @v_rpe GEMM (overlays all)
//  asb  @22272  [128][40]  per-head att_out staging for incremental proj
//  xs   @0      [128][136] initial x staging (freed after frag caching)
__global__ __launch_bounds__(256, 2) void wa_attn(
    const float* __restrict__ x,
    const float* __restrict__ qkv_b, const float* __restrict__ proj_b,
    const ushort* __restrict__ wb, const ushort* __restrict__ pwb,
    const ushort* __restrict__ rpeb, const ushort* __restrict__ tvt,
    const ushort* __restrict__ mskT,
    float* __restrict__ out)
{
  __shared__ __align__(16) ushort sm[29184];

  const int tid  = threadIdx.x;
  const int lane = tid & 63;
  const int wv   = tid >> 6;
  const int m16  = lane & 15;
  const int q4   = lane >> 4;
  const int b    = blockIdx.x;
  const int wi   = b & 127;
  const int row0 = wv * 32;
  const ushort* mskp = mskT + ((size_t)wi << 14);
  const f32x4 z4 = {0.f, 0.f, 0.f, 0.f};

  // ---- P0: stage x -> bf16 LDS (wave-local rows), cache A-frags in regs
  {
    int r = tid >> 1, hf = tid & 1;
    const float* src = x + (size_t)b * 16384 + r * 128 + hf * 64;
    ushort* dst = sm + r * 136 + hf * 64;
#pragma unroll
    for (int it = 0; it < 16; ++it){
      float4 f = *(const float4*)(src + it * 4);
      dst[it*4+0] = f2bf(f.x); dst[it*4+1] = f2bf(f.y);
      dst[it*4+2] = f2bf(f.z); dst[it*4+3] = f2bf(f.w);
    }
  }
  bf16x8 xf[2][4];
#pragma unroll
  for (int mt = 0; mt < 2; ++mt)
#pragma unroll
    for (int kk = 0; kk < 4; ++kk)
      xf[mt][kk] = ld16(sm + (row0 + mt*16 + m16)*136 + kk*32 + q4*8);
  __syncthreads();                                   // #0: xs region freed

  f32x4 po[2][8];
#pragma unroll
  for (int mt = 0; mt < 2; ++mt)
#pragma unroll
    for (int nt = 0; nt < 8; ++nt) po[mt][nt] = z4;

#pragma unroll
  for (int h = 0; h < 4; ++h){
    ushort* qsl = sm + row0 * 72;                    // in own SQR slab, stride 40
    ushort* ksl = sm + 9216 + wv * 2176;             // in own SVK slab, stride 40
    ushort* vts = sm + 17920;                        // [32][136]

    // ---- P1: qkv GEMM [128,128]@[128,96] for head h
    {
      f32x4 aqk[2][6];
#pragma unroll
      for (int mt = 0; mt < 2; ++mt)
#pragma unroll
        for (int nt = 0; nt < 6; ++nt) aqk[mt][nt] = z4;
#pragma unroll
      for (int kk = 0; kk < 4; ++kk)
#pragma unroll
        for (int nt = 0; nt < 6; ++nt){
          int obase = (nt >> 1)*128 + h*32 + (nt & 1)*16;
          bf16x8 bf = ld16(wb + (obase + m16)*128 + kk*32 + q4*8);
#pragma unroll
          for (int mt = 0; mt < 2; ++mt) aqk[mt][nt] = mfma16(xf[mt][kk], bf, aqk[mt][nt]);
        }
#pragma unroll
      for (int nt = 0; nt < 6; ++nt){
        int part = nt >> 1;
        int colb = (nt & 1)*16 + m16;
        float bias = qkv_b[part*128 + h*32 + colb];
#pragma unroll
        for (int mt = 0; mt < 2; ++mt){
          int rb0 = mt*16 + q4*4;                    // band-relative row
#pragma unroll
          for (int r = 0; r < 4; ++r){
            float v = aqk[mt][nt][r] + bias;
            if (part == 0)      qsl[(rb0+r)*40 + colb] = f2bf(v * SCALE);
            else if (part == 1) ksl[(rb0+r)*40 + colb] = f2bf(v);
            else                vts[colb*136 + row0 + rb0 + r] = f2bf(v);
          }
        }
      }
    }
    bf16x8 afq[2], afk[2];
#pragma unroll
    for (int mt = 0; mt < 2; ++mt){
      afq[mt] = ld16(qsl + (mt*16 + m16)*40 + q4*8);
      afk[mt] = ld16(ksl + (mt*16 + m16)*40 + q4*8);
    }
    // ---- P2: U = q.k_rpe -> scatter into SQR (own rows; overwrites qsl bytes)
#pragma unroll
    for (int nt = 0; nt < 15; ++nt){
      bf16x8 bf = ld16(rpeb + (nt*16 + m16)*384 + 128 + h*32 + q4*8);
      int r225 = nt*16 + m16;
      int a = r225 / 15, bb = r225 % 15;
#pragma unroll
      for (int mt = 0; mt < 2; ++mt){
        f32x4 d = mfma16(afq[mt], bf, z4);
        int rb = row0 + mt*16 + q4*4;
#pragma unroll
        for (int r = 0; r < 4; ++r){
          int ip = (rb + r) >> 1;
          int jpr = (ip >> 3) - a + 7, jpc = (ip & 7) - bb + 7;
          if (((unsigned)jpr < 8u) & ((unsigned)jpc < 8u))
            sm[(rb + r)*72 + jpc*8 + jpr] = f2bf(d[r]);
        }
      }
    }
    __syncthreads();                                 // #2: ks + vts visible

    // ---- P3: qk MFMA + gather A (mask f16 + SQR), all via ld16
    f32x4 S[2][8];
#pragma unroll
    for (int nt = 0; nt < 8; ++nt){
      int j = nt*16 + m16;
      bf16x8 bk = ld16(sm + 9216 + (j >> 5)*2176 + (j & 31)*40 + q4*8);
#pragma unroll
      for (int mt = 0; mt < 2; ++mt) S[mt][nt] = mfma16(afq[mt], bk, z4);
    }
#pragma unroll
    for (int mt = 0; mt < 2; ++mt){
      int rb = row0 + mt*16 + q4*4;
#pragma unroll
      for (int r = 0; r < 4; ++r){
        int i = rb + r;
        f16x8 mk = ldh16(mskp + i*128 + m16*8);
        s16x8 sq = __builtin_bit_cast(s16x8, ld16(sm + i*72 + (m16 >> 1)*8));
#pragma unroll
        for (int nt = 0; nt < 8; ++nt)
          S[mt][nt][r] += (float)mk[nt] + bf2f((ushort)sq[nt]);
      }
    }
    __syncthreads();                                 // #1: ks readers done

    // ---- P4: V = k.(scale q_rpe) -> scatter into SVK (rows ip any, cols own)
#pragma unroll
    for (int nt = 0; nt < 15; ++nt){
      bf16x8 bf = ld16(rpeb + (nt*16 + m16)*384 + h*32 + q4*8);
      int r225 = nt*16 + m16;
      int a = r225 / 15, bb = r225 % 15;
#pragma unroll
      for (int mt = 0; mt < 2; ++mt){
        f32x4 d = mfma16(afk[mt], bf, z4);
        int rb = row0 + mt*16 + q4*4;
#pragma unroll
        for (int r = 0; r < 4; ++r){
          int j = rb + r, jp = j >> 1;
          int ipr = (jp >> 3) + a - 7, ipc = (jp & 7) + bb - 7;
          if (((unsigned)ipr < 8u) & ((unsigned)ipc < 8u))
            sm[9216 + (ipr*8 + ipc)*136 + (j & 15)*8 + (j >> 4)] = f2bf(d[r]);
        }
      }
    }
    __syncthreads();                                 // #3: SVK complete

    // ---- P5: gather B (SVK ld16) + softmax; keep p in S regs
#pragma unroll
    for (int mt = 0; mt < 2; ++mt){
      int rb = row0 + mt*16 + q4*4;
#pragma unroll
      for (int r = 0; r < 4; ++r){
        int ip = (rb + r) >> 1;
        s16x8 sv = __builtin_bit_cast(s16x8, ld16(sm + 9216 + ip*136 + m16*8));
#pragma unroll
        for (int nt = 0; nt < 8; ++nt) S[mt][nt][r] += bf2f((ushort)sv[nt]);
      }
    }
#pragma unroll
    for (int mt = 0; mt < 2; ++mt)
#pragma unroll
      for (int r = 0; r < 4; ++r){
        float mx = S[mt][0][r];
#pragma unroll
        for (int nt = 1; nt < 8; ++nt) mx = fmaxf(mx, S[mt][nt][r]);
        mx = fmaxf(mx, __shfl_xor(mx, 1));
        mx = fmaxf(mx, __shfl_xor(mx, 2));
        mx = fmaxf(mx, __shfl_xor(mx, 4));
        mx = fmaxf(mx, __shfl_xor(mx, 8));
        float sum = 0.f;
#pragma unroll
        for (int nt = 0; nt < 8; ++nt){
          float e = exp2f((S[mt][nt][r] - mx) * 1.44269504089f);
          S[mt][nt][r] = e; sum += e;
        }
        sum += __shfl_xor(sum, 1);
        sum += __shfl_xor(sum, 2);
        sum += __shfl_xor(sum, 4);
        sum += __shfl_xor(sum, 8);
        float inv = __builtin_amdgcn_rcpf(sum);
#pragma unroll
        for (int nt = 0; nt < 8; ++nt) S[mt][nt][r] *= inv;   // S now holds p
      }
    __syncthreads();                                 // #4: SVK readers done
    // write p -> ps (overlays SQR+SVK)
#pragma unroll
    for (int mt = 0; mt < 2; ++mt){
      int rb = row0 + mt*16 + q4*4;
#pragma unroll
      for (int r = 0; r < 4; ++r)
#pragma unroll
        for (int nt = 0; nt < 8; ++nt)
          sm[(rb + r)*136 + nt*16 + m16] = f2bf(S[mt][nt][r]);
    }
    // ---- P6: out1 = p @ v
    f32x4 ao[2][2];
#pragma unroll
    for (int mt = 0; mt < 2; ++mt)
#pragma unroll
      for (int nt = 0; nt < 2; ++nt) ao[mt][nt] = z4;
#pragma unroll
    for (int kk = 0; kk < 4; ++kk){
      bf16x8 ap[2];
#pragma unroll
      for (int mt = 0; mt < 2; ++mt)
        ap[mt] = ld16(sm + (row0 + mt*16 + m16)*136 + kk*32 + q4*8);
#pragma unroll
      for (int nt = 0; nt < 2; ++nt){
        bf16x8 bv = ld16(vts + (nt*16 + m16)*136 + kk*32 + q4*8);
#pragma unroll
        for (int mt = 0; mt < 2; ++mt) ao[mt][nt] = mfma16(ap[mt], bv, ao[mt][nt]);
      }
    }
    __syncthreads();                                 // #5: ps/vts readers done

    // ---- P7: W zero (own rows) + p2 scatter (wave-local) + GEMM + fixup
    {
      uint* wz = (uint*)sm;
#pragma unroll
      for (int it = 0; it < 57; ++it) wz[row0*114 + it*64 + lane] = 0;
    }
#pragma unroll
    for (int mt = 0; mt < 2; ++mt){
      int rb = row0 + mt*16 + q4*4;
#pragma unroll
      for (int nt = 0; nt < 8; ++nt)
#pragma unroll
        for (int r = 0; r < 4; ++r){
          float pv = S[mt][nt][r];
          float p2 = pv + __shfl_xor(pv, 1);
          if (!(m16 & 1)){
            int i = rb + r, ip = i >> 1;
            int rr = ((ip >> 3) - nt + 7)*15 + ((ip & 7) - (m16 >> 1) + 7);
            sm[i*228 + rr] = f2bf(p2);
          }
        }
    }
#pragma unroll
    for (int kk = 0; kk < 7; ++kk){
      bf16x8 aw[2];
#pragma unroll
      for (int mt = 0; mt < 2; ++mt)
        aw[mt] = ld8(sm + (row0 + mt*16 + m16)*228 + kk*32 + q4*8);
#pragma unroll
      for (int nt = 0; nt < 2; ++nt){
        bf16x8 bt = ld16(tvt + (h*32 + nt*16 + m16)*240 + kk*32 + q4*8);
#pragma unroll
        for (int mt = 0; mt < 2; ++mt) ao[mt][nt] = mfma16(aw[mt], bt, ao[mt][nt]);
      }
    }
#pragma unroll
    for (int nt = 0; nt < 2; ++nt){
      float tvv = bf2f(tvt[(h*32 + nt*16 + m16)*240 + 224]);
#pragma unroll
      for (int mt = 0; mt < 2; ++mt){
        int rb = row0 + mt*16 + q4*4;
#pragma unroll
        for (int r = 0; r < 4; ++r)
          ao[mt][nt][r] += bf2f(sm[(rb + r)*228 + 224]) * tvv;
      }
    }
    __syncthreads();                                 // #6: W readers done

    // ---- P8: stage att_out (C->A layout) + incremental proj kk-step
    {
      ushort* asb = sm + 22272;                      // [128][40]
#pragma unroll
      for (int nt = 0; nt < 2; ++nt)
#pragma unroll
        for (int mt = 0; mt < 2; ++mt){
          int rb = row0 + mt*16 + q4*4;
#pragma unroll
          for (int r = 0; r < 4; ++r)
            asb[(rb + r)*40 + nt*16 + m16] = f2bf(ao[mt][nt][r]);
        }
      bf16x8 afA[2];
#pragma unroll
      for (int mt = 0; mt < 2; ++mt)
        afA[mt] = ld16(asb + (row0 + mt*16 + m16)*40 + q4*8);
#pragma unroll
      for (int nt = 0; nt < 8; ++nt){
        bf16x8 bw = ld16(pwb + (nt*16 + m16)*128 + h*32 + q4*8);
#pragma unroll
        for (int mt = 0; mt < 2; ++mt) po[mt][nt] = mfma16(afA[mt], bw, po[mt][nt]);
      }
    }
  } // heads

  // ---- epilogue: out = po + bias
  float* outb = out + (size_t)b * 16384;
#pragma unroll
  for (int nt = 0; nt < 8; ++nt){
    int o = nt*16 + m16;
    float bias = proj_b[o];
#pragma unroll
    for (int mt = 0; mt < 2; ++mt){
      int rb = row0 + mt*16 + q4*4;
#pragma unroll
      for (int r = 0; r < 4; ++r) outb[(rb + r)*128 + o] = po[mt][nt][r] + bias;
    }
  }
}

extern "C" void kernel_launch(void* const* d_in, const int* in_sizes, int n_in,
                              void* d_out, int out_size, void* d_ws, size_t ws_size,
                              hipStream_t stream){
  (void)in_sizes; (void)n_in; (void)out_size; (void)ws_size;
  const float* x      = (const float*)d_in[0];
  const float* mask   = (const float*)d_in[1];
  const float* qkv_w  = (const float*)d_in[2];
  const float* qkv_b  = (const float*)d_in[3];
  const float* rpe    = (const float*)d_in[4];
  const float* proj_w = (const float*)d_in[5];
  const float* proj_b = (const float*)d_in[6];

  ushort* wb   = (ushort*)d_ws;            // 49152
  ushort* pwb  = wb + 49152;               // 16384
  ushort* rpeb = pwb + 16384;              // 92160
  ushort* tvt  = rpeb + 92160;             // 30720
  ushort* mskT = tvt + 30720;              // 2097152 f16  (total ~4.57 MB)

  wa_prep<<<360, 256, 0, stream>>>(qkv_w, rpe, proj_w, wb, pwb, rpeb, tvt);
  wa_prep_mask<<<8192, 256, 0, stream>>>(mask, mskT);
  wa_attn<<<2048, 256, 0, stream>>>(x, qkv_b, proj_b, wb, pwb, rpeb, tvt, mskT,
                                    (float*)d_out);
}